// Round 14
// baseline (108.284 us; speedup 1.0000x reference)
//
#include <hip/hip_runtime.h>
#include <stdint.h>

typedef __attribute__((ext_vector_type(8))) short bf16x8;
typedef __attribute__((ext_vector_type(4))) float f32x4;
typedef __attribute__((ext_vector_type(4))) unsigned int u32x4;

#define MFMA16(a, b, c) __builtin_amdgcn_mfma_f32_16x16x32_bf16(a, b, c, 0, 0, 0)

__device__ __forceinline__ float bf2f(unsigned short u) {
    union { unsigned int i; float f; } x; x.i = ((unsigned int)u) << 16; return x.f;
}
__device__ __forceinline__ unsigned short f2bf(float f) {
    union { float f; unsigned int i; } x; x.f = f;
    unsigned int u = x.i;
    return (unsigned short)((u + 0x7FFFu + ((u >> 16) & 1u)) >> 16);
}

// ---------------- P: merged prep (cvt | wt | sc), one launch ----------------
// bid < 8192: hs f32 -> bf16 (BW-bound). next 192: W transpose. last: sin/cos.
// wt/sc run under cvt's bandwidth shadow instead of serially.
__global__ __launch_bounds__(256) void k_prep(const float4* __restrict__ in,
                                              unsigned short* __restrict__ out,
                                              const float* __restrict__ W0,
                                              const float* __restrict__ W1,
                                              const float* __restrict__ W2,
                                              unsigned short* __restrict__ Wt,
                                              float* __restrict__ cs2) {
    __shared__ float t[64][65];
    const int bid = blockIdx.x;
    if (bid < 8192) {
        int i = bid * 256 + threadIdx.x;
        float4 v = in[i];
        ushort4 o;
        o.x = f2bf(v.x); o.y = f2bf(v.y); o.z = f2bf(v.z); o.w = f2bf(v.w);
        *(ushort4*)(out + (size_t)i * 4) = o;
    } else if (bid < 8192 + 192) {
        int w = bid - 8192;
        int k0 = (w & 7) * 64, n0 = ((w >> 3) & 7) * 64, mz = w >> 6;
        const float* Wm = (mz == 0) ? W0 : (mz == 1) ? W1 : W2;
        for (int it = 0; it < 16; ++it) {
            int idx = threadIdx.x + it * 256;
            int r = idx >> 6, c = idx & 63;
            t[r][c] = Wm[(k0 + r) * 512 + n0 + c];
        }
        __syncthreads();
        unsigned short* dst = Wt + (size_t)mz * 512 * 512;
        for (int it = 0; it < 16; ++it) {
            int idx = threadIdx.x + it * 256;
            int nr = idx >> 6, kc = idx & 63;
            dst[(n0 + nr) * 512 + k0 + kc] = f2bf(t[kc][nr]);
        }
    } else {
        int s = threadIdx.x;
        for (int f = 0; f < 16; ++f) {
            float inv = powf(10000.0f, -(float)f / 16.0f);
            float a = (float)s * inv;
            cs2[(s * 16 + f) * 2 + 0] = cosf(a);
            cs2[(s * 16 + f) * 2 + 1] = sinf(a);
        }
    }
}

// ---------------- G: QKV GEMM (R11 geometry + tri-buffer single-barrier schedule) ----------------
// 128x128 tile, BK=64, THREE LDS buffers (48KB, still 2 blocks/CU), (256,2).
// One barrier per K-step: a wave at barrier(kt) has finished reading
// buf[(kt-1)%3] (ds_reads complete before its iter kt-1 MFMAs issue), so the
// refill of tile kt+2 into that buffer is WAR-safe without a second barrier.
// vmcnt(8) waits only the tile about to be consumed; next tile stays in flight.
__global__ __launch_bounds__(256, 2) void k_gemm(
    const unsigned short* __restrict__ A,   // hsb [16384][512] bf16
    const unsigned short* __restrict__ Bw,  // wt  [1536][512] bf16 ([n][k])
    const float* __restrict__ bq, const float* __restrict__ bk, const float* __restrict__ bv,
    const float* __restrict__ cs2,
    unsigned short* __restrict__ Qo, unsigned short* __restrict__ Ko, unsigned short* __restrict__ Vo) {
    __shared__ unsigned short a_l[3][8192];
    __shared__ unsigned short b_l[3][8192];
    const int tid = threadIdx.x;
    const int wave = tid >> 6, lane = tid & 63;
    const int l15 = lane & 15, l4 = lane >> 4;
    // XCD-chunked swizzle: 1536 blocks = 8 XCDs x 192 (16 m-tiles each, n fast)
    int bid = blockIdx.x;
    int swz = (bid & 7) * 192 + (bid >> 3);
    const int m0 = (swz / 12) * 128;
    const int n0 = (swz % 12) * 128;
    const int wm = (wave >> 1) * 64, wn = (wave & 1) * 64;
    const bool isV = (n0 >= 1024);

    f32x4 zero4 = {0.f, 0.f, 0.f, 0.f};
    f32x4 acc[4][4];
#pragma unroll
    for (int i = 0; i < 4; ++i)
#pragma unroll
        for (int j = 0; j < 4; ++j) acc[i][j] = zero4;

    // staging: thread t covers row (t>>3)+32*it, source k-chunk XOR-preswizzled
    const int srow = tid >> 3;
    const int skc = ((tid & 7) ^ (srow & 7)) * 8;
    const unsigned short* ga = A + (size_t)(m0 + srow) * 512 + skc;
    const unsigned short* gb = Bw + (size_t)(n0 + srow) * 512 + skc;

#define STAGE(buf, kt)                                                                          \
    {                                                                                           \
        const unsigned short* pa = ga + (kt) * 64;                                              \
        const unsigned short* pb = gb + (kt) * 64;                                              \
        unsigned short* la = &a_l[(buf)][wave * 512];                                           \
        unsigned short* lb = &b_l[(buf)][wave * 512];                                           \
        _Pragma("unroll")                                                                       \
        for (int it = 0; it < 4; ++it) {                                                        \
            __builtin_amdgcn_global_load_lds(                                                   \
                (const __attribute__((address_space(1))) unsigned int*)(pa + it * (32 * 512)),  \
                (__attribute__((address_space(3))) unsigned int*)(la + it * 2048), 16, 0, 0);   \
            __builtin_amdgcn_global_load_lds(                                                   \
                (const __attribute__((address_space(1))) unsigned int*)(pb + it * (32 * 512)),  \
                (__attribute__((address_space(3))) unsigned int*)(lb + it * 2048), 16, 0, 0);   \
        }                                                                                       \
    }

    STAGE(0, 0);
    STAGE(1, 1);                     // 16 loads in flight
    for (int kt = 0; kt < 8; ++kt) {
        const int cur = kt % 3;
        // wait ONLY tile kt (8 older loads); tile kt+1's 8 stay in flight.
        if (kt < 7) { asm volatile("s_waitcnt vmcnt(8)" ::: "memory"); }
        else        { asm volatile("s_waitcnt vmcnt(0)" ::: "memory"); }
        __builtin_amdgcn_s_barrier();
        // refill tile kt+2 into buf[(kt+2)%3] = buf[(kt-1)%3]: all waves past the
        // barrier have finished reading it (their iter kt-1 MFMAs consumed it).
        if (kt < 6) STAGE((kt + 2) % 3, kt + 2);
#pragma unroll
        for (int kc = 0; kc < 2; ++kc) {
            bf16x8 af[4], bfr[4];
#pragma unroll
            for (int i = 0; i < 4; ++i) {
                int g = ((kc * 4 + l4) ^ (l15 & 7)) * 8;   // read-side XOR
                af[i] = *(const bf16x8*)&a_l[cur][(wm + i * 16 + l15) * 64 + g];
            }
#pragma unroll
            for (int j = 0; j < 4; ++j) {
                int g = ((kc * 4 + l4) ^ (l15 & 7)) * 8;
                bfr[j] = *(const bf16x8*)&b_l[cur][(wn + j * 16 + l15) * 64 + g];
            }
            if (!isV) {
#pragma unroll
                for (int i = 0; i < 4; ++i)
#pragma unroll
                    for (int j = 0; j < 4; ++j) acc[i][j] = MFMA16(af[i], bfr[j], acc[i][j]);
            } else {
                // swapped operands: D[n_local][m_local] -> transposed V output
#pragma unroll
                for (int i = 0; i < 4; ++i)
#pragma unroll
                    for (int j = 0; j < 4; ++j) acc[i][j] = MFMA16(bfr[j], af[i], acc[i][j]);
            }
        }
    }
#undef STAGE

    if (!isV) {
        const int mat = n0 >> 9;  // 0=Q, 1=K
        unsigned short* __restrict__ dst = (mat == 0) ? Qo : Ko;
        const float* __restrict__ bias = (mat == 0) ? bq : bk;
#pragma unroll
        for (int j = 0; j < 4; ++j) {
            int col = (n0 & 511) + wn + j * 16 + l15;  // 0..511
            float bb = bias[col];
            int h = col >> 5, dh = col & 31, f = dh >> 1;
            float sgn = (col & 1) ? 1.0f : -1.0f;
#pragma unroll
            for (int i = 0; i < 4; ++i) {
#pragma unroll
                for (int r = 0; r < 4; ++r) {
                    int m = m0 + wm + i * 16 + l4 * 4 + r;
                    int b2 = m >> 8, s = m & 255;
                    float t = acc[i][j][r] + bb;
                    float partner = __shfl_xor(t, 1);
                    float2 cn = *(const float2*)(cs2 + (s * 16 + f) * 2);
                    float o = t * cn.x + sgn * partner * cn.y;
                    dst[(size_t)(b2 * 16 + h) * 8192 + s * 32 + dh] = f2bf(o);
                }
            }
        }
    } else {
        // V: acc[i][j] = D[n_local = wn+j*16+l4*4+r][m_local = wm+i*16+l15]
#pragma unroll
        for (int j = 0; j < 4; ++j) {
#pragma unroll
            for (int r = 0; r < 4; ++r) {
                int n = (n0 & 511) + wn + j * 16 + l4 * 4 + r;  // 0..511
                float bb = bv[n];
                int h = n >> 5, dh = n & 31;
#pragma unroll
                for (int i = 0; i < 4; ++i) {
                    int m = m0 + wm + i * 16 + l15;
                    int b2 = m >> 8, s = m & 255;
                    Vo[(size_t)(b2 * 16 + h) * 8192 + dh * 256 + s] = f2bf(acc[i][j][r] + bb);
                }
            }
        }
    }
}

// ---------------- A: attention (R12/13 version + T5 setprio on MFMA clusters) ----------------
__global__ __launch_bounds__(256, 3) void k_attn(
    const unsigned short* __restrict__ Qm, const unsigned short* __restrict__ Km,
    const unsigned short* __restrict__ Vm,  // Vm is [b][h][dh][s]
    const float* __restrict__ bias_table, float* __restrict__ out) {
    __shared__ unsigned short k_l[256 * 32];   // linear [s][dh], conflict-free (4-chunk rows)
    __shared__ unsigned short vt_l[32 * 256];  // linear [dh][s], chunk-XOR swizzled content
    __shared__ float bias_g[512];              // rel-bias slice, all 4 q0 offsets (0..510)

    const int tid = threadIdx.x, wave = tid >> 6, lane = tid & 63;
    const int l15 = lane & 15, l4 = lane >> 4;
    // 1024 blocks = 8 XCDs x 128
    int bid = blockIdx.x;
    int swz = (bid & 7) * 128 + (bid >> 3);
    const int h = swz & 15, b = swz >> 4;
    const size_t bh = ((size_t)(b * 16 + h)) * 8192;

    for (int i = tid; i < 511; i += 256) bias_g[i] = bias_table[i * 16 + h];

    // K stage: straight 16KB copy via global_load_lds
#pragma unroll
    for (int it = 0; it < 4; ++it) {
        int p = it * 256 + wave * 64 + lane;  // 16B chunk index
        __builtin_amdgcn_global_load_lds(
            (const __attribute__((address_space(1))) unsigned int*)(Km + bh + p * 8),
            (__attribute__((address_space(3))) unsigned int*)(k_l + it * 2048 + wave * 512), 16, 0, 0);
    }
    // V stage: source pre-swizzled (chunk c at lds pos c^(dh&7))
#pragma unroll
    for (int it = 0; it < 4; ++it) {
        int p = it * 256 + wave * 64 + lane;
        int dh = p >> 5, cpos = p & 31;
        int srcc = cpos ^ (dh & 7);
        __builtin_amdgcn_global_load_lds(
            (const __attribute__((address_space(1))) unsigned int*)(Vm + bh + dh * 256 + srcc * 8),
            (__attribute__((address_space(3))) unsigned int*)(vt_l + it * 2048 + wave * 512), 16, 0, 0);
    }
    __syncthreads();
    // k_l / vt_l / bias_g read-only from here -> no more barriers.

    f32x4 zero4 = {0.f, 0.f, 0.f, 0.f};
    const float SCL2 = 0.17677669529663687f * 1.4426950408889634f;
    const int qrow = 16 * wave + l15;
    const bool hi = (l4 >> 1) != 0;   // a
    const bool odd = (l4 & 1) != 0;   // b

    bf16x8 qcur = *(const bf16x8*)(Qm + bh + (size_t)qrow * 32 + l4 * 8);  // qb=0

    for (int qb = 0; qb < 4; ++qb) {
        const int q0 = qb * 64;
        bf16x8 qnext;
        if (qb < 3)  // issue next Q load now; consumed next iteration (hidden)
            qnext = *(const bf16x8*)(Qm + bh + (size_t)(q0 + 64 + qrow) * 32 + l4 * 8);

        // QK^T swapped: sc[ct] holds scores(k = 16ct+4*l4+r, q = q0+16w+l15)
        f32x4 sc[16];
        __builtin_amdgcn_s_setprio(1);
#pragma unroll
        for (int ct = 0; ct < 16; ++ct) {
            bf16x8 kf = *(const bf16x8*)&k_l[(ct * 16 + l15) * 32 + l4 * 8];
            sc[ct] = MFMA16(kf, qcur, zero4);
        }
        __builtin_amdgcn_s_setprio(0);

        // softmax, 4-way partial sums (breaks the 64-long dependent add chain)
        float s0 = 0.f, s1 = 0.f, s2 = 0.f, s3 = 0.f;
#pragma unroll
        for (int ct = 0; ct < 16; ++ct) {
            float e0, e1, e2, e3;
            float x0 = sc[ct][0] * SCL2, x1 = sc[ct][1] * SCL2;
            float x2 = sc[ct][2] * SCL2, x3 = sc[ct][3] * SCL2;
            asm("v_exp_f32 %0, %1" : "=v"(e0) : "v"(x0));
            asm("v_exp_f32 %0, %1" : "=v"(e1) : "v"(x1));
            asm("v_exp_f32 %0, %1" : "=v"(e2) : "v"(x2));
            asm("v_exp_f32 %0, %1" : "=v"(e3) : "v"(x3));
            sc[ct][0] = e0; sc[ct][1] = e1; sc[ct][2] = e2; sc[ct][3] = e3;
            s0 += e0; s1 += e1; s2 += e2; s3 += e3;
        }
        float sum = (s0 + s1) + (s2 + s3);
        sum += __shfl_xor(sum, 16);
        sum += __shfl_xor(sum, 32);
        float inv = 1.0f / sum;

        // PV with in-register P-redistribution (acc layout -> A-frag layout)
        f32x4 o0 = zero4, o1 = zero4;
#pragma unroll
        for (int m = 0; m < 8; ++m) {
            unsigned int E0, E1, O0, O1;
            {
                int kbase = 32 * m + 4 * l4;
                int jb = q0 + qrow - kbase + 255;
                float p0 = sc[2 * m][0] * inv + bias_g[jb];
                float p1 = sc[2 * m][1] * inv + bias_g[jb - 1];
                float p2 = sc[2 * m][2] * inv + bias_g[jb - 2];
                float p3 = sc[2 * m][3] * inv + bias_g[jb - 3];
                asm("v_cvt_pk_bf16_f32 %0, %1, %2" : "=v"(E0) : "v"(p0), "v"(p1));
                asm("v_cvt_pk_bf16_f32 %0, %1, %2" : "=v"(E1) : "v"(p2), "v"(p3));
                jb -= 16;
                p0 = sc[2 * m + 1][0] * inv + bias_g[jb];
                p1 = sc[2 * m + 1][1] * inv + bias_g[jb - 1];
                p2 = sc[2 * m + 1][2] * inv + bias_g[jb - 2];
                p3 = sc[2 * m + 1][3] * inv + bias_g[jb - 3];
                asm("v_cvt_pk_bf16_f32 %0, %1, %2" : "=v"(O0) : "v"(p0), "v"(p1));
                asm("v_cvt_pk_bf16_f32 %0, %1, %2" : "=v"(O1) : "v"(p2), "v"(p3));
            }
            unsigned int m0_ = hi ? O0 : E0, m1_ = hi ? O1 : E1;  // own parity-a pair
            unsigned int s0_ = hi ? E0 : O0, s1_ = hi ? E1 : O1;  // give-away pair
            unsigned int g0 = __shfl_xor(s0_, 32), g1 = __shfl_xor(s1_, 32);
            unsigned int X00 = hi ? g0 : m0_, X01 = hi ? g1 : m1_;  // (a'=0, b'=b)
            unsigned int X10 = hi ? m0_ : g0, X11 = hi ? m1_ : g1;  // (a'=1, b'=b)
            unsigned int k0 = odd ? X10 : X00, k1 = odd ? X11 : X01;  // keep (a'=b)
            unsigned int t0 = odd ? X00 : X10, t1 = odd ? X01 : X11;  // send (a'=1-b)
            unsigned int r0 = __shfl_xor(t0, 16), r1 = __shfl_xor(t1, 16);
            union { unsigned int u[4]; bf16x8 v; } pu;
            pu.u[0] = odd ? r0 : k0; pu.u[1] = odd ? r1 : k1;   // b'=0 source
            pu.u[2] = odd ? k0 : r0; pu.u[3] = odd ? k1 : r1;   // b'=1 source
            int vc = (m * 4 + l4) ^ (l15 & 7);
            bf16x8 v0 = *(const bf16x8*)&vt_l[l15 * 256 + vc * 8];
            bf16x8 v1 = *(const bf16x8*)&vt_l[(16 + l15) * 256 + vc * 8];
            __builtin_amdgcn_s_setprio(1);
            o0 = MFMA16(pu.v, v0, o0);
            o1 = MFMA16(pu.v, v1, o1);
            __builtin_amdgcn_s_setprio(0);
        }

        // write out[b][s][h*32+dh] f32
#pragma unroll
        for (int r = 0; r < 4; ++r) {
            int s = q0 + 16 * wave + l4 * 4 + r;
            float* po = out + ((size_t)(b * 256 + s)) * 512 + h * 32;
            po[l15] = o0[r];
            po[16 + l15] = o1[r];
        }
        if (qb < 3) qcur = qnext;
    }
}

// ---------------- launch ----------------
extern "C" void kernel_launch(void* const* d_in, const int* in_sizes, int n_in,
                              void* d_out, int out_size, void* d_ws, size_t ws_size,
                              hipStream_t stream) {
    const float* hs = (const float*)d_in[0];
    const float* Wq = (const float*)d_in[1];
    const float* bq = (const float*)d_in[2];
    const float* Wk = (const float*)d_in[3];
    const float* bk = (const float*)d_in[4];
    const float* Wv = (const float*)d_in[5];
    const float* bv = (const float*)d_in[6];
    const float* bt = (const float*)d_in[7];
    float* out = (float*)d_out;

    char* ws = (char*)d_ws;
    unsigned short* hsb = (unsigned short*)ws;                 // 16,777,216 B (row-major bf16)
    unsigned short* wt = (unsigned short*)(ws + 16777216);     //  1,572,864 B ([n][k] row-major)
    unsigned short* Qo = (unsigned short*)(ws + 18350080);     // 16,777,216 B
    unsigned short* Ko = (unsigned short*)(ws + 35127296);     // 16,777,216 B
    unsigned short* Vo = (unsigned short*)(ws + 51904512);     // 16,777,216 B ([b][h][dh][s])
    float* cs2 = (float*)(ws + 68681728);                      //     32,768 B

    hipLaunchKernelGGL(k_prep, dim3(8192 + 192 + 1), dim3(256), 0, stream,
                       (const float4*)hs, hsb, Wq, Wk, Wv, wt, cs2);
    hipLaunchKernelGGL(k_gemm, dim3(1536), dim3(256), 0, stream,
                       hsb, wt, bq, bk, bv, cs2, Qo, Ko, Vo);
    hipLaunchKernelGGL(k_attn, dim3(1024), dim3(256), 0, stream,
                       Qo, Ko, Vo, bt, out);
}

// Round 15
// 93.935 us; speedup vs baseline: 1.1527x; 1.1527x over previous
//
#include <hip/hip_runtime.h>
#include <stdint.h>

typedef __attribute__((ext_vector_type(8))) short bf16x8;
typedef __attribute__((ext_vector_type(4))) float f32x4;
typedef __attribute__((ext_vector_type(4))) unsigned int u32x4;

#define MFMA16(a, b, c) __builtin_amdgcn_mfma_f32_16x16x32_bf16(a, b, c, 0, 0, 0)

__device__ __forceinline__ float bf2f(unsigned short u) {
    union { unsigned int i; float f; } x; x.i = ((unsigned int)u) << 16; return x.f;
}
__device__ __forceinline__ unsigned short f2bf(float f) {
    union { float f; unsigned int i; } x; x.f = f;
    unsigned int u = x.i;
    return (unsigned short)((u + 0x7FFFu + ((u >> 16) & 1u)) >> 16);
}

// ---------------- P1: hs f32 -> bf16 ----------------
__global__ __launch_bounds__(256) void k_cvt(const float4* __restrict__ in,
                                             unsigned short* __restrict__ out) {
    int i = blockIdx.x * 256 + threadIdx.x;
    float4 v = in[i];
    ushort4 o;
    o.x = f2bf(v.x); o.y = f2bf(v.y); o.z = f2bf(v.z); o.w = f2bf(v.w);
    *(ushort4*)(out + (size_t)i * 4) = o;
}

// ---------------- P2: W [k][n] f32 -> Wt [n][k] bf16 (3 mats) ----------------
__global__ __launch_bounds__(256) void k_wt(const float* __restrict__ W0,
                                            const float* __restrict__ W1,
                                            const float* __restrict__ W2,
                                            unsigned short* __restrict__ Wt) {
    __shared__ float t[64][65];
    const float* Wm = (blockIdx.z == 0) ? W0 : (blockIdx.z == 1) ? W1 : W2;
    int k0 = blockIdx.x * 64, n0 = blockIdx.y * 64;
    for (int it = 0; it < 16; ++it) {
        int idx = threadIdx.x + it * 256;
        int r = idx >> 6, c = idx & 63;
        t[r][c] = Wm[(k0 + r) * 512 + n0 + c];
    }
    __syncthreads();
    unsigned short* dst = Wt + (size_t)blockIdx.z * 512 * 512;
    for (int it = 0; it < 16; ++it) {
        int idx = threadIdx.x + it * 256;
        int nr = idx >> 6, kc = idx & 63;
        dst[(n0 + nr) * 512 + k0 + kc] = f2bf(t[kc][nr]);
    }
}

// ---------------- P3: RoPE cos/sin interleaved table [256][16][2] ----------------
__global__ __launch_bounds__(256) void k_sc(float* __restrict__ cs2) {
    int s = threadIdx.x;
    for (int f = 0; f < 16; ++f) {
        float inv = powf(10000.0f, -(float)f / 16.0f);
        float a = (float)s * inv;
        cs2[(s * 16 + f) * 2 + 0] = cosf(a);
        cs2[(s * 16 + f) * 2 + 1] = sinf(a);
    }
}

// ---------------- G: QKV GEMM (R13 verbatim -- measured best 44.4 us) ----------------
// 128x128 tile, BK=64, dbuf LDS A+B, (256,2), counted vmcnt(8) + 2 barriers/step.
// R14's tri-buffer (96KB LDS -> 1 block/CU, 57.6us) proved the 2nd resident
// block is what hides the residual latency -- do not grow LDS past 64KB.
__global__ __launch_bounds__(256, 2) void k_gemm(
    const unsigned short* __restrict__ A,   // hsb [16384][512] bf16
    const unsigned short* __restrict__ Bw,  // wt  [1536][512] bf16 ([n][k])
    const float* __restrict__ bq, const float* __restrict__ bk, const float* __restrict__ bv,
    const float* __restrict__ cs2,
    unsigned short* __restrict__ Qo, unsigned short* __restrict__ Ko, unsigned short* __restrict__ Vo) {
    __shared__ unsigned short a_l[2][8192];
    __shared__ unsigned short b_l[2][8192];
    const int tid = threadIdx.x;
    const int wave = tid >> 6, lane = tid & 63;
    const int l15 = lane & 15, l4 = lane >> 4;
    // XCD-chunked swizzle: 1536 blocks = 8 XCDs x 192 (16 m-tiles each, n fast)
    int bid = blockIdx.x;
    int swz = (bid & 7) * 192 + (bid >> 3);
    const int m0 = (swz / 12) * 128;
    const int n0 = (swz % 12) * 128;
    const int wm = (wave >> 1) * 64, wn = (wave & 1) * 64;
    const bool isV = (n0 >= 1024);

    f32x4 zero4 = {0.f, 0.f, 0.f, 0.f};
    f32x4 acc[4][4];
#pragma unroll
    for (int i = 0; i < 4; ++i)
#pragma unroll
        for (int j = 0; j < 4; ++j) acc[i][j] = zero4;

    // staging: thread t covers row (t>>3)+32*it, source k-chunk XOR-preswizzled
    const int srow = tid >> 3;
    const int skc = ((tid & 7) ^ (srow & 7)) * 8;
    const unsigned short* ga = A + (size_t)(m0 + srow) * 512 + skc;
    const unsigned short* gb = Bw + (size_t)(n0 + srow) * 512 + skc;

#define STAGE(buf, kt)                                                                          \
    {                                                                                           \
        const unsigned short* pa = ga + (kt) * 64;                                              \
        const unsigned short* pb = gb + (kt) * 64;                                              \
        unsigned short* la = &a_l[(buf)][wave * 512];                                           \
        unsigned short* lb = &b_l[(buf)][wave * 512];                                           \
        _Pragma("unroll")                                                                       \
        for (int it = 0; it < 4; ++it) {                                                        \
            __builtin_amdgcn_global_load_lds(                                                   \
                (const __attribute__((address_space(1))) unsigned int*)(pa + it * (32 * 512)),  \
                (__attribute__((address_space(3))) unsigned int*)(la + it * 2048), 16, 0, 0);   \
            __builtin_amdgcn_global_load_lds(                                                   \
                (const __attribute__((address_space(1))) unsigned int*)(pb + it * (32 * 512)),  \
                (__attribute__((address_space(3))) unsigned int*)(lb + it * 2048), 16, 0, 0);   \
        }                                                                                       \
    }

    STAGE(0, 0);
    STAGE(1, 1);                     // 16 loads in flight
    int cur = 0;
    for (int kt = 0; kt < 8; ++kt) {
        // barrier1: wait ONLY tile kt (8 older loads); tile kt+1's 8 stay in flight.
        if (kt < 7) { asm volatile("s_waitcnt vmcnt(8)" ::: "memory"); }
        else        { asm volatile("s_waitcnt vmcnt(0)" ::: "memory"); }
        __builtin_amdgcn_s_barrier();
#pragma unroll
        for (int kc = 0; kc < 2; ++kc) {
            bf16x8 af[4], bfr[4];
#pragma unroll
            for (int i = 0; i < 4; ++i) {
                int g = ((kc * 4 + l4) ^ (l15 & 7)) * 8;   // read-side XOR
                af[i] = *(const bf16x8*)&a_l[cur][(wm + i * 16 + l15) * 64 + g];
            }
#pragma unroll
            for (int j = 0; j < 4; ++j) {
                int g = ((kc * 4 + l4) ^ (l15 & 7)) * 8;
                bfr[j] = *(const bf16x8*)&b_l[cur][(wn + j * 16 + l15) * 64 + g];
            }
            if (!isV) {
#pragma unroll
                for (int i = 0; i < 4; ++i)
#pragma unroll
                    for (int j = 0; j < 4; ++j) acc[i][j] = MFMA16(af[i], bfr[j], acc[i][j]);
            } else {
                // swapped operands: D[n_local][m_local] -> transposed V output
#pragma unroll
                for (int i = 0; i < 4; ++i)
#pragma unroll
                    for (int j = 0; j < 4; ++j) acc[i][j] = MFMA16(bfr[j], af[i], acc[i][j]);
            }
        }
        // barrier2: all waves done reading buf[cur]; refill gets a full iteration.
        asm volatile("" ::: "memory");
        __builtin_amdgcn_s_barrier();
        if (kt < 6) STAGE(cur, kt + 2);
        cur ^= 1;
    }
#undef STAGE

    if (!isV) {
        const int mat = n0 >> 9;  // 0=Q, 1=K
        unsigned short* __restrict__ dst = (mat == 0) ? Qo : Ko;
        const float* __restrict__ bias = (mat == 0) ? bq : bk;
#pragma unroll
        for (int j = 0; j < 4; ++j) {
            int col = (n0 & 511) + wn + j * 16 + l15;  // 0..511
            float bb = bias[col];
            int h = col >> 5, dh = col & 31, f = dh >> 1;
            float sgn = (col & 1) ? 1.0f : -1.0f;
#pragma unroll
            for (int i = 0; i < 4; ++i) {
#pragma unroll
                for (int r = 0; r < 4; ++r) {
                    int m = m0 + wm + i * 16 + l4 * 4 + r;
                    int b2 = m >> 8, s = m & 255;
                    float t = acc[i][j][r] + bb;
                    float partner = __shfl_xor(t, 1);
                    float2 cn = *(const float2*)(cs2 + (s * 16 + f) * 2);
                    float o = t * cn.x + sgn * partner * cn.y;
                    dst[(size_t)(b2 * 16 + h) * 8192 + s * 32 + dh] = f2bf(o);
                }
            }
        }
    } else {
        // V: acc[i][j] = D[n_local = wn+j*16+l4*4+r][m_local = wm+i*16+l15]
#pragma unroll
        for (int j = 0; j < 4; ++j) {
#pragma unroll
            for (int r = 0; r < 4; ++r) {
                int n = (n0 & 511) + wn + j * 16 + l4 * 4 + r;  // 0..511
                float bb = bv[n];
                int h = n >> 5, dh = n & 31;
#pragma unroll
                for (int i = 0; i < 4; ++i) {
                    int m = m0 + wm + i * 16 + l15;
                    int b2 = m >> 8, s = m & 255;
                    Vo[(size_t)(b2 * 16 + h) * 8192 + dh * 256 + s] = f2bf(acc[i][j][r] + bb);
                }
            }
        }
    }
}

// ---------------- A: attention (R13 version + nontemporal out stores) ----------------
// out is write-once/never-read: nt stores skip L2 allocation, preserving the
// XCD's L2 for Q/K/V lines shared by the 16 co-XCD (b,h) blocks.
__global__ __launch_bounds__(256, 3) void k_attn(
    const unsigned short* __restrict__ Qm, const unsigned short* __restrict__ Km,
    const unsigned short* __restrict__ Vm,  // Vm is [b][h][dh][s]
    const float* __restrict__ bias_table, float* __restrict__ out) {
    __shared__ unsigned short k_l[256 * 32];   // linear [s][dh], conflict-free (4-chunk rows)
    __shared__ unsigned short vt_l[32 * 256];  // linear [dh][s], chunk-XOR swizzled content
    __shared__ float bias_g[512];              // rel-bias slice, all 4 q0 offsets (0..510)

    const int tid = threadIdx.x, wave = tid >> 6, lane = tid & 63;
    const int l15 = lane & 15, l4 = lane >> 4;
    // 1024 blocks = 8 XCDs x 128
    int bid = blockIdx.x;
    int swz = (bid & 7) * 128 + (bid >> 3);
    const int h = swz & 15, b = swz >> 4;
    const size_t bh = ((size_t)(b * 16 + h)) * 8192;

    for (int i = tid; i < 511; i += 256) bias_g[i] = bias_table[i * 16 + h];

    // K stage: straight 16KB copy via global_load_lds
#pragma unroll
    for (int it = 0; it < 4; ++it) {
        int p = it * 256 + wave * 64 + lane;  // 16B chunk index
        __builtin_amdgcn_global_load_lds(
            (const __attribute__((address_space(1))) unsigned int*)(Km + bh + p * 8),
            (__attribute__((address_space(3))) unsigned int*)(k_l + it * 2048 + wave * 512), 16, 0, 0);
    }
    // V stage: source pre-swizzled (chunk c at lds pos c^(dh&7))
#pragma unroll
    for (int it = 0; it < 4; ++it) {
        int p = it * 256 + wave * 64 + lane;
        int dh = p >> 5, cpos = p & 31;
        int srcc = cpos ^ (dh & 7);
        __builtin_amdgcn_global_load_lds(
            (const __attribute__((address_space(1))) unsigned int*)(Vm + bh + dh * 256 + srcc * 8),
            (__attribute__((address_space(3))) unsigned int*)(vt_l + it * 2048 + wave * 512), 16, 0, 0);
    }
    __syncthreads();
    // k_l / vt_l / bias_g read-only from here -> no more barriers.

    f32x4 zero4 = {0.f, 0.f, 0.f, 0.f};
    const float SCL2 = 0.17677669529663687f * 1.4426950408889634f;
    const int qrow = 16 * wave + l15;
    const bool hi = (l4 >> 1) != 0;   // a
    const bool odd = (l4 & 1) != 0;   // b

    bf16x8 qcur = *(const bf16x8*)(Qm + bh + (size_t)qrow * 32 + l4 * 8);  // qb=0

    for (int qb = 0; qb < 4; ++qb) {
        const int q0 = qb * 64;
        bf16x8 qnext;
        if (qb < 3)  // issue next Q load now; consumed next iteration (hidden)
            qnext = *(const bf16x8*)(Qm + bh + (size_t)(q0 + 64 + qrow) * 32 + l4 * 8);

        // QK^T swapped: sc[ct] holds scores(k = 16ct+4*l4+r, q = q0+16w+l15)
        f32x4 sc[16];
#pragma unroll
        for (int ct = 0; ct < 16; ++ct) {
            bf16x8 kf = *(const bf16x8*)&k_l[(ct * 16 + l15) * 32 + l4 * 8];
            sc[ct] = MFMA16(kf, qcur, zero4);
        }

        // softmax, 4-way partial sums (breaks the 64-long dependent add chain)
        float s0 = 0.f, s1 = 0.f, s2 = 0.f, s3 = 0.f;
#pragma unroll
        for (int ct = 0; ct < 16; ++ct) {
            float e0, e1, e2, e3;
            float x0 = sc[ct][0] * SCL2, x1 = sc[ct][1] * SCL2;
            float x2 = sc[ct][2] * SCL2, x3 = sc[ct][3] * SCL2;
            asm("v_exp_f32 %0, %1" : "=v"(e0) : "v"(x0));
            asm("v_exp_f32 %0, %1" : "=v"(e1) : "v"(x1));
            asm("v_exp_f32 %0, %1" : "=v"(e2) : "v"(x2));
            asm("v_exp_f32 %0, %1" : "=v"(e3) : "v"(x3));
            sc[ct][0] = e0; sc[ct][1] = e1; sc[ct][2] = e2; sc[ct][3] = e3;
            s0 += e0; s1 += e1; s2 += e2; s3 += e3;
        }
        float sum = (s0 + s1) + (s2 + s3);
        sum += __shfl_xor(sum, 16);
        sum += __shfl_xor(sum, 32);
        float inv = 1.0f / sum;

        // PV with in-register P-redistribution (acc layout -> A-frag layout)
        f32x4 o0 = zero4, o1 = zero4;
#pragma unroll
        for (int m = 0; m < 8; ++m) {
            unsigned int E0, E1, O0, O1;
            {
                int kbase = 32 * m + 4 * l4;
                int jb = q0 + qrow - kbase + 255;
                float p0 = sc[2 * m][0] * inv + bias_g[jb];
                float p1 = sc[2 * m][1] * inv + bias_g[jb - 1];
                float p2 = sc[2 * m][2] * inv + bias_g[jb - 2];
                float p3 = sc[2 * m][3] * inv + bias_g[jb - 3];
                asm("v_cvt_pk_bf16_f32 %0, %1, %2" : "=v"(E0) : "v"(p0), "v"(p1));
                asm("v_cvt_pk_bf16_f32 %0, %1, %2" : "=v"(E1) : "v"(p2), "v"(p3));
                jb -= 16;
                p0 = sc[2 * m + 1][0] * inv + bias_g[jb];
                p1 = sc[2 * m + 1][1] * inv + bias_g[jb - 1];
                p2 = sc[2 * m + 1][2] * inv + bias_g[jb - 2];
                p3 = sc[2 * m + 1][3] * inv + bias_g[jb - 3];
                asm("v_cvt_pk_bf16_f32 %0, %1, %2" : "=v"(O0) : "v"(p0), "v"(p1));
                asm("v_cvt_pk_bf16_f32 %0, %1, %2" : "=v"(O1) : "v"(p2), "v"(p3));
            }
            unsigned int m0_ = hi ? O0 : E0, m1_ = hi ? O1 : E1;  // own parity-a pair
            unsigned int s0_ = hi ? E0 : O0, s1_ = hi ? E1 : O1;  // give-away pair
            unsigned int g0 = __shfl_xor(s0_, 32), g1 = __shfl_xor(s1_, 32);
            unsigned int X00 = hi ? g0 : m0_, X01 = hi ? g1 : m1_;  // (a'=0, b'=b)
            unsigned int X10 = hi ? m0_ : g0, X11 = hi ? m1_ : g1;  // (a'=1, b'=b)
            unsigned int k0 = odd ? X10 : X00, k1 = odd ? X11 : X01;  // keep (a'=b)
            unsigned int t0 = odd ? X00 : X10, t1 = odd ? X01 : X11;  // send (a'=1-b)
            unsigned int r0 = __shfl_xor(t0, 16), r1 = __shfl_xor(t1, 16);
            union { unsigned int u[4]; bf16x8 v; } pu;
            pu.u[0] = odd ? r0 : k0; pu.u[1] = odd ? r1 : k1;   // b'=0 source
            pu.u[2] = odd ? k0 : r0; pu.u[3] = odd ? k1 : r1;   // b'=1 source
            int vc = (m * 4 + l4) ^ (l15 & 7);
            bf16x8 v0 = *(const bf16x8*)&vt_l[l15 * 256 + vc * 8];
            bf16x8 v1 = *(const bf16x8*)&vt_l[(16 + l15) * 256 + vc * 8];
            o0 = MFMA16(pu.v, v0, o0);
            o1 = MFMA16(pu.v, v1, o1);
        }

        // write out[b][s][h*32+dh] f32 -- nontemporal (write-once, never re-read)
#pragma unroll
        for (int r = 0; r < 4; ++r) {
            int s = q0 + 16 * wave + l4 * 4 + r;
            float* po = out + ((size_t)(b * 256 + s)) * 512 + h * 32;
            __builtin_nontemporal_store(o0[r], po + l15);
            __builtin_nontemporal_store(o1[r], po + 16 + l15);
        }
        if (qb < 3) qcur = qnext;
    }
}

// ---------------- launch ----------------
extern "C" void kernel_launch(void* const* d_in, const int* in_sizes, int n_in,
                              void* d_out, int out_size, void* d_ws, size_t ws_size,
                              hipStream_t stream) {
    const float* hs = (const float*)d_in[0];
    const float* Wq = (const float*)d_in[1];
    const float* bq = (const float*)d_in[2];
    const float* Wk = (const float*)d_in[3];
    const float* bk = (const float*)d_in[4];
    const float* Wv = (const float*)d_in[5];
    const float* bv = (const float*)d_in[6];
    const float* bt = (const float*)d_in[7];
    float* out = (float*)d_out;

    char* ws = (char*)d_ws;
    unsigned short* hsb = (unsigned short*)ws;                 // 16,777,216 B (row-major bf16)
    unsigned short* wt = (unsigned short*)(ws + 16777216);     //  1,572,864 B ([n][k] row-major)
    unsigned short* Qo = (unsigned short*)(ws + 18350080);     // 16,777,216 B
    unsigned short* Ko = (unsigned short*)(ws + 35127296);     // 16,777,216 B
    unsigned short* Vo = (unsigned short*)(ws + 51904512);     // 16,777,216 B ([b][h][dh][s])
    float* cs2 = (float*)(ws + 68681728);                      //     32,768 B

    hipLaunchKernelGGL(k_cvt, dim3(8192), dim3(256), 0, stream, (const float4*)hs, hsb);
    hipLaunchKernelGGL(k_wt, dim3(8, 8, 3), dim3(256), 0, stream, Wq, Wk, Wv, wt);
    hipLaunchKernelGGL(k_sc, dim3(1), dim3(256), 0, stream, cs2);
    hipLaunchKernelGGL(k_gemm, dim3(1536), dim3(256), 0, stream,
                       hsb, wt, bq, bk, bv, cs2, Qo, Ko, Vo);
    hipLaunchKernelGGL(k_attn, dim3(1024), dim3(256), 0, stream,
                       Qo, Ko, Vo, bt, out);
}

// Round 16
// 89.503 us; speedup vs baseline: 1.2098x; 1.0495x over previous
//
#include <hip/hip_runtime.h>
#include <stdint.h>

typedef __attribute__((ext_vector_type(8))) short bf16x8;
typedef __attribute__((ext_vector_type(4))) float f32x4;
typedef __attribute__((ext_vector_type(4))) unsigned int u32x4;

#define MFMA16(a, b, c) __builtin_amdgcn_mfma_f32_16x16x32_bf16(a, b, c, 0, 0, 0)

__device__ __forceinline__ float bf2f(unsigned short u) {
    union { unsigned int i; float f; } x; x.i = ((unsigned int)u) << 16; return x.f;
}
__device__ __forceinline__ unsigned short f2bf(float f) {
    union { float f; unsigned int i; } x; x.f = f;
    unsigned int u = x.i;
    return (unsigned short)((u + 0x7FFFu + ((u >> 16) & 1u)) >> 16);
}

// ---------------- P1: hs f32 -> bf16 ----------------
__global__ __launch_bounds__(256) void k_cvt(const float4* __restrict__ in,
                                             unsigned short* __restrict__ out) {
    int i = blockIdx.x * 256 + threadIdx.x;
    float4 v = in[i];
    ushort4 o;
    o.x = f2bf(v.x); o.y = f2bf(v.y); o.z = f2bf(v.z); o.w = f2bf(v.w);
    *(ushort4*)(out + (size_t)i * 4) = o;
}

// ---------------- P2: W [k][n] f32 -> Wt [n][k] bf16 (3 mats) ----------------
__global__ __launch_bounds__(256) void k_wt(const float* __restrict__ W0,
                                            const float* __restrict__ W1,
                                            const float* __restrict__ W2,
                                            unsigned short* __restrict__ Wt) {
    __shared__ float t[64][65];
    const float* Wm = (blockIdx.z == 0) ? W0 : (blockIdx.z == 1) ? W1 : W2;
    int k0 = blockIdx.x * 64, n0 = blockIdx.y * 64;
    for (int it = 0; it < 16; ++it) {
        int idx = threadIdx.x + it * 256;
        int r = idx >> 6, c = idx & 63;
        t[r][c] = Wm[(k0 + r) * 512 + n0 + c];
    }
    __syncthreads();
    unsigned short* dst = Wt + (size_t)blockIdx.z * 512 * 512;
    for (int it = 0; it < 16; ++it) {
        int idx = threadIdx.x + it * 256;
        int nr = idx >> 6, kc = idx & 63;
        dst[(n0 + nr) * 512 + k0 + kc] = f2bf(t[kc][nr]);
    }
}

// ---------------- P3: RoPE cos/sin interleaved table [256][16][2] ----------------
__global__ __launch_bounds__(256) void k_sc(float* __restrict__ cs2) {
    int s = threadIdx.x;
    for (int f = 0; f < 16; ++f) {
        float inv = powf(10000.0f, -(float)f / 16.0f);
        float a = (float)s * inv;
        cs2[(s * 16 + f) * 2 + 0] = cosf(a);
        cs2[(s * 16 + f) * 2 + 1] = sinf(a);
    }
}

// ---------------- G: QKV GEMM (R13 verbatim -- measured best 44.4 us) ----------------
__global__ __launch_bounds__(256, 2) void k_gemm(
    const unsigned short* __restrict__ A,   // hsb [16384][512] bf16
    const unsigned short* __restrict__ Bw,  // wt  [1536][512] bf16 ([n][k])
    const float* __restrict__ bq, const float* __restrict__ bk, const float* __restrict__ bv,
    const float* __restrict__ cs2,
    unsigned short* __restrict__ Qo, unsigned short* __restrict__ Ko, unsigned short* __restrict__ Vo) {
    __shared__ unsigned short a_l[2][8192];
    __shared__ unsigned short b_l[2][8192];
    const int tid = threadIdx.x;
    const int wave = tid >> 6, lane = tid & 63;
    const int l15 = lane & 15, l4 = lane >> 4;
    // XCD-chunked swizzle: 1536 blocks = 8 XCDs x 192 (16 m-tiles each, n fast)
    int bid = blockIdx.x;
    int swz = (bid & 7) * 192 + (bid >> 3);
    const int m0 = (swz / 12) * 128;
    const int n0 = (swz % 12) * 128;
    const int wm = (wave >> 1) * 64, wn = (wave & 1) * 64;
    const bool isV = (n0 >= 1024);

    f32x4 zero4 = {0.f, 0.f, 0.f, 0.f};
    f32x4 acc[4][4];
#pragma unroll
    for (int i = 0; i < 4; ++i)
#pragma unroll
        for (int j = 0; j < 4; ++j) acc[i][j] = zero4;

    // staging: thread t covers row (t>>3)+32*it, source k-chunk XOR-preswizzled
    const int srow = tid >> 3;
    const int skc = ((tid & 7) ^ (srow & 7)) * 8;
    const unsigned short* ga = A + (size_t)(m0 + srow) * 512 + skc;
    const unsigned short* gb = Bw + (size_t)(n0 + srow) * 512 + skc;

#define STAGE(buf, kt)                                                                          \
    {                                                                                           \
        const unsigned short* pa = ga + (kt) * 64;                                              \
        const unsigned short* pb = gb + (kt) * 64;                                              \
        unsigned short* la = &a_l[(buf)][wave * 512];                                           \
        unsigned short* lb = &b_l[(buf)][wave * 512];                                           \
        _Pragma("unroll")                                                                       \
        for (int it = 0; it < 4; ++it) {                                                        \
            __builtin_amdgcn_global_load_lds(                                                   \
                (const __attribute__((address_space(1))) unsigned int*)(pa + it * (32 * 512)),  \
                (__attribute__((address_space(3))) unsigned int*)(la + it * 2048), 16, 0, 0);   \
            __builtin_amdgcn_global_load_lds(                                                   \
                (const __attribute__((address_space(1))) unsigned int*)(pb + it * (32 * 512)),  \
                (__attribute__((address_space(3))) unsigned int*)(lb + it * 2048), 16, 0, 0);   \
        }                                                                                       \
    }

    STAGE(0, 0);
    STAGE(1, 1);                     // 16 loads in flight
    int cur = 0;
    for (int kt = 0; kt < 8; ++kt) {
        // barrier1: wait ONLY tile kt (8 older loads); tile kt+1's 8 stay in flight.
        if (kt < 7) { asm volatile("s_waitcnt vmcnt(8)" ::: "memory"); }
        else        { asm volatile("s_waitcnt vmcnt(0)" ::: "memory"); }
        __builtin_amdgcn_s_barrier();
#pragma unroll
        for (int kc = 0; kc < 2; ++kc) {
            bf16x8 af[4], bfr[4];
#pragma unroll
            for (int i = 0; i < 4; ++i) {
                int g = ((kc * 4 + l4) ^ (l15 & 7)) * 8;   // read-side XOR
                af[i] = *(const bf16x8*)&a_l[cur][(wm + i * 16 + l15) * 64 + g];
            }
#pragma unroll
            for (int j = 0; j < 4; ++j) {
                int g = ((kc * 4 + l4) ^ (l15 & 7)) * 8;
                bfr[j] = *(const bf16x8*)&b_l[cur][(wn + j * 16 + l15) * 64 + g];
            }
            if (!isV) {
#pragma unroll
                for (int i = 0; i < 4; ++i)
#pragma unroll
                    for (int j = 0; j < 4; ++j) acc[i][j] = MFMA16(af[i], bfr[j], acc[i][j]);
            } else {
                // swapped operands: D[n_local][m_local] -> transposed V output
#pragma unroll
                for (int i = 0; i < 4; ++i)
#pragma unroll
                    for (int j = 0; j < 4; ++j) acc[i][j] = MFMA16(bfr[j], af[i], acc[i][j]);
            }
        }
        // barrier2: all waves done reading buf[cur]; refill gets a full iteration.
        asm volatile("" ::: "memory");
        __builtin_amdgcn_s_barrier();
        if (kt < 6) STAGE(cur, kt + 2);
        cur ^= 1;
    }
#undef STAGE

    if (!isV) {
        const int mat = n0 >> 9;  // 0=Q, 1=K
        unsigned short* __restrict__ dst = (mat == 0) ? Qo : Ko;
        const float* __restrict__ bias = (mat == 0) ? bq : bk;
#pragma unroll
        for (int j = 0; j < 4; ++j) {
            int col = (n0 & 511) + wn + j * 16 + l15;  // 0..511
            float bb = bias[col];
            int h = col >> 5, dh = col & 31, f = dh >> 1;
            float sgn = (col & 1) ? 1.0f : -1.0f;
#pragma unroll
            for (int i = 0; i < 4; ++i) {
#pragma unroll
                for (int r = 0; r < 4; ++r) {
                    int m = m0 + wm + i * 16 + l4 * 4 + r;
                    int b2 = m >> 8, s = m & 255;
                    float t = acc[i][j][r] + bb;
                    float partner = __shfl_xor(t, 1);
                    float2 cn = *(const float2*)(cs2 + (s * 16 + f) * 2);
                    float o = t * cn.x + sgn * partner * cn.y;
                    dst[(size_t)(b2 * 16 + h) * 8192 + s * 32 + dh] = f2bf(o);
                }
            }
        }
    } else {
        // V: acc[i][j] = D[n_local = wn+j*16+l4*4+r][m_local = wm+i*16+l15]
#pragma unroll
        for (int j = 0; j < 4; ++j) {
#pragma unroll
            for (int r = 0; r < 4; ++r) {
                int n = (n0 & 511) + wn + j * 16 + l4 * 4 + r;  // 0..511
                float bb = bv[n];
                int h = n >> 5, dh = n & 31;
#pragma unroll
                for (int i = 0; i < 4; ++i) {
                    int m = m0 + wm + i * 16 + l15;
                    int b2 = m >> 8, s = m & 255;
                    Vo[(size_t)(b2 * 16 + h) * 8192 + dh * 256 + s] = f2bf(acc[i][j][r] + bb);
                }
            }
        }
    }
}

// ---------------- A: attention, normalize-after-PV ----------------
// ctx = inv*(sum_k exp*V) + (sum_k bias*V):  PV consumes exp immediately per
// 32-k window (sc lifetime = 1 m-iter, not whole qb -> ~90 reg demand), softmax
// sum/rcp moves OFF the critical path (applied to f32 output), bias term is its
// own MFMA accumulator fed by consecutive-entry reads of a reversed bf16 table.
// (256,4): 4 blocks/CU, 16 waves/CU (R8's spill was demand>128; now ~90).
__global__ __launch_bounds__(256, 4) void k_attn(
    const unsigned short* __restrict__ Qm, const unsigned short* __restrict__ Km,
    const unsigned short* __restrict__ Vm,  // Vm is [b][h][dh][s]
    const float* __restrict__ bias_table, float* __restrict__ out) {
    __shared__ unsigned short k_l[256 * 32];   // linear [s][dh], conflict-free (4-chunk rows)
    __shared__ unsigned short vt_l[32 * 256];  // linear [dh][s], chunk-XOR swizzled content
    __shared__ __align__(16) unsigned short brE[512];  // brE[j] = bf16(bias[510-j])
    __shared__ __align__(16) unsigned short brO[512];  // brO[j] = brE-value[j+1]

    const int tid = threadIdx.x, wave = tid >> 6, lane = tid & 63;
    const int l15 = lane & 15, l4 = lane >> 4;
    // 1024 blocks = 8 XCDs x 128
    int bid = blockIdx.x;
    int swz = (bid & 7) * 128 + (bid >> 3);
    const int h = swz & 15, b = swz >> 4;
    const size_t bh = ((size_t)(b * 16 + h)) * 8192;

    // reversed bias tables: bias[x] = bias_table[x*16+h]; value[j] = bias[510-j]
    for (int x = tid; x < 511; x += 256) {
        unsigned short w = f2bf(bias_table[x * 16 + h]);
        brE[510 - x] = w;                  // brE[j] = value[j]
        if (x <= 509) brO[509 - x] = w;    // brO[j] = value[j+1]
    }

    // K stage: straight 16KB copy via global_load_lds
#pragma unroll
    for (int it = 0; it < 4; ++it) {
        int p = it * 256 + wave * 64 + lane;  // 16B chunk index
        __builtin_amdgcn_global_load_lds(
            (const __attribute__((address_space(1))) unsigned int*)(Km + bh + p * 8),
            (__attribute__((address_space(3))) unsigned int*)(k_l + it * 2048 + wave * 512), 16, 0, 0);
    }
    // V stage: source pre-swizzled (chunk c at lds pos c^(dh&7))
#pragma unroll
    for (int it = 0; it < 4; ++it) {
        int p = it * 256 + wave * 64 + lane;
        int dh = p >> 5, cpos = p & 31;
        int srcc = cpos ^ (dh & 7);
        __builtin_amdgcn_global_load_lds(
            (const __attribute__((address_space(1))) unsigned int*)(Vm + bh + dh * 256 + srcc * 8),
            (__attribute__((address_space(3))) unsigned int*)(vt_l + it * 2048 + wave * 512), 16, 0, 0);
    }
    __syncthreads();
    // k_l / vt_l / brE / brO read-only from here -> no more barriers.

    f32x4 zero4 = {0.f, 0.f, 0.f, 0.f};
    const float SCL2 = 0.17677669529663687f * 1.4426950408889634f;
    const int qrow = 16 * wave + l15;
    const bool hi = (l4 >> 1) != 0;   // a
    const bool odd = (l4 & 1) != 0;   // b

    bf16x8 qcur = *(const bf16x8*)(Qm + bh + (size_t)qrow * 32 + l4 * 8);  // qb=0

    for (int qb = 0; qb < 4; ++qb) {
        const int q0 = qb * 64;
        bf16x8 qnext;
        if (qb < 3)
            qnext = *(const bf16x8*)(Qm + bh + (size_t)(q0 + 64 + qrow) * 32 + l4 * 8);

        f32x4 o0 = zero4, o1 = zero4;    // sum exp*V (unnormalized)
        f32x4 c20 = zero4, c21 = zero4;  // sum bias*V
        float s0 = 0.f, s1 = 0.f, s2 = 0.f, s3 = 0.f;

#pragma unroll
        for (int m = 0; m < 8; ++m) {
            // QK^T (swapped) for the two 16-col groups of this 32-k window
            bf16x8 kf0 = *(const bf16x8*)&k_l[((2 * m) * 16 + l15) * 32 + l4 * 8];
            bf16x8 kf1 = *(const bf16x8*)&k_l[((2 * m + 1) * 16 + l15) * 32 + l4 * 8];
            f32x4 sca = MFMA16(kf0, qcur, zero4);
            f32x4 scb = MFMA16(kf1, qcur, zero4);
            // exp (unnormalized), 4-way partial sums
            float e0, e1, e2, e3, e4, e5, e6, e7;
            {
                float x0 = sca[0] * SCL2, x1 = sca[1] * SCL2, x2 = sca[2] * SCL2, x3 = sca[3] * SCL2;
                float x4 = scb[0] * SCL2, x5 = scb[1] * SCL2, x6 = scb[2] * SCL2, x7 = scb[3] * SCL2;
                asm("v_exp_f32 %0, %1" : "=v"(e0) : "v"(x0));
                asm("v_exp_f32 %0, %1" : "=v"(e1) : "v"(x1));
                asm("v_exp_f32 %0, %1" : "=v"(e2) : "v"(x2));
                asm("v_exp_f32 %0, %1" : "=v"(e3) : "v"(x3));
                asm("v_exp_f32 %0, %1" : "=v"(e4) : "v"(x4));
                asm("v_exp_f32 %0, %1" : "=v"(e5) : "v"(x5));
                asm("v_exp_f32 %0, %1" : "=v"(e6) : "v"(x6));
                asm("v_exp_f32 %0, %1" : "=v"(e7) : "v"(x7));
            }
            s0 += e0 + e4; s1 += e1 + e5; s2 += e2 + e6; s3 += e3 + e7;
            // pack to bf16 and redistribute acc-layout -> A-frag layout
            unsigned int E0, E1, O0, O1;
            asm("v_cvt_pk_bf16_f32 %0, %1, %2" : "=v"(E0) : "v"(e0), "v"(e1));
            asm("v_cvt_pk_bf16_f32 %0, %1, %2" : "=v"(E1) : "v"(e2), "v"(e3));
            asm("v_cvt_pk_bf16_f32 %0, %1, %2" : "=v"(O0) : "v"(e4), "v"(e5));
            asm("v_cvt_pk_bf16_f32 %0, %1, %2" : "=v"(O1) : "v"(e6), "v"(e7));
            unsigned int m0_ = hi ? O0 : E0, m1_ = hi ? O1 : E1;  // own parity-a pair
            unsigned int s0_ = hi ? E0 : O0, s1_ = hi ? E1 : O1;  // give-away pair
            unsigned int g0 = __shfl_xor(s0_, 32), g1 = __shfl_xor(s1_, 32);
            unsigned int X00 = hi ? g0 : m0_, X01 = hi ? g1 : m1_;  // (a'=0, b'=b)
            unsigned int X10 = hi ? m0_ : g0, X11 = hi ? m1_ : g1;  // (a'=1, b'=b)
            unsigned int k0 = odd ? X10 : X00, k1 = odd ? X11 : X01;  // keep (a'=b)
            unsigned int t0 = odd ? X00 : X10, t1 = odd ? X01 : X11;  // send (a'=1-b)
            unsigned int r0 = __shfl_xor(t0, 16), r1 = __shfl_xor(t1, 16);
            union { unsigned int u[4]; bf16x8 v; } pu;
            pu.u[0] = odd ? r0 : k0; pu.u[1] = odd ? r1 : k1;   // b'=0 source
            pu.u[2] = odd ? k0 : r0; pu.u[3] = odd ? k1 : r1;   // b'=1 source
            // bias A-frag: bias[q-k+255] for k=32m+8*l4+e, e=0..7 (consecutive in
            // the reversed table; parity-pair arrays keep reads dword-aligned)
            union { unsigned int u[4]; bf16x8 v; } bu;
            {
                int c = 255 + 32 * m + 8 * l4 - (q0 + qrow);
                const unsigned short* arr = (c & 1) ? brO : brE;
                int cb = c & ~1;
                bu.u[0] = *(const unsigned int*)&arr[cb];
                bu.u[1] = *(const unsigned int*)&arr[cb + 2];
                bu.u[2] = *(const unsigned int*)&arr[cb + 4];
                bu.u[3] = *(const unsigned int*)&arr[cb + 6];
            }
            // shared V fragments feed both accumulators
            int vc = (m * 4 + l4) ^ (l15 & 7);
            bf16x8 v0 = *(const bf16x8*)&vt_l[l15 * 256 + vc * 8];
            bf16x8 v1 = *(const bf16x8*)&vt_l[(16 + l15) * 256 + vc * 8];
            o0 = MFMA16(pu.v, v0, o0);
            o1 = MFMA16(pu.v, v1, o1);
            c20 = MFMA16(bu.v, v0, c20);
            c21 = MFMA16(bu.v, v1, c21);
        }

        // row sums -> inv, off the critical path (PV already done)
        float sum = (s0 + s1) + (s2 + s3);
        sum += __shfl_xor(sum, 16);
        sum += __shfl_xor(sum, 32);
        float inv = 1.0f / sum;   // per q = q0+16w+l15; uniform over l4

        // write out[b][s][h*32+dh] f32, nontemporal; inv for C-row q=q0+16w+4*l4+r
#pragma unroll
        for (int r = 0; r < 4; ++r) {
            float ivr = __shfl(inv, 4 * l4 + r);   // lane with l15 = 4*l4+r
            int s = q0 + 16 * wave + l4 * 4 + r;
            float* po = out + ((size_t)(b * 256 + s)) * 512 + h * 32;
            __builtin_nontemporal_store(o0[r] * ivr + c20[r], po + l15);
            __builtin_nontemporal_store(o1[r] * ivr + c21[r], po + 16 + l15);
        }
        if (qb < 3) qcur = qnext;
    }
}

// ---------------- launch ----------------
extern "C" void kernel_launch(void* const* d_in, const int* in_sizes, int n_in,
                              void* d_out, int out_size, void* d_ws, size_t ws_size,
                              hipStream_t stream) {
    const float* hs = (const float*)d_in[0];
    const float* Wq = (const float*)d_in[1];
    const float* bq = (const float*)d_in[2];
    const float* Wk = (const float*)d_in[3];
    const float* bk = (const float*)d_in[4];
    const float* Wv = (const float*)d_in[5];
    const float* bv = (const float*)d_in[6];
    const float* bt = (const float*)d_in[7];
    float* out = (float*)d_out;

    char* ws = (char*)d_ws;
    unsigned short* hsb = (unsigned short*)ws;                 // 16,777,216 B (row-major bf16)
    unsigned short* wt = (unsigned short*)(ws + 16777216);     //  1,572,864 B ([n][k] row-major)
    unsigned short* Qo = (unsigned short*)(ws + 18350080);     // 16,777,216 B
    unsigned short* Ko = (unsigned short*)(ws + 35127296);     // 16,777,216 B
    unsigned short* Vo = (unsigned short*)(ws + 51904512);     // 16,777,216 B ([b][h][dh][s])
    float* cs2 = (float*)(ws + 68681728);                      //     32,768 B

    hipLaunchKernelGGL(k_cvt, dim3(8192), dim3(256), 0, stream, (const float4*)hs, hsb);
    hipLaunchKernelGGL(k_wt, dim3(8, 8, 3), dim3(256), 0, stream, Wq, Wk, Wv, wt);
    hipLaunchKernelGGL(k_sc, dim3(1), dim3(256), 0, stream, cs2);
    hipLaunchKernelGGL(k_gemm, dim3(1536), dim3(256), 0, stream,
                       hsb, wt, bq, bk, bv, cs2, Qo, Ko, Vo);
    hipLaunchKernelGGL(k_attn, dim3(1024), dim3(256), 0, stream,
                       Qo, Ko, Vo, bt, out);
}